// Round 8
// baseline (506.328 us; speedup 1.0000x reference)
//
#include <hip/hip_runtime.h>
#include <hip/hip_bf16.h>
#include <math.h>

// ce[n] = 0.5 * (LSE(x[n,:]) + LSE(y[n,:]) - max_c(x[n,c]+y[n,c]))
// out   = mean_n ce[n]
//
// One WAVE (64 lanes) per row of C=2048: each lane owns 32 elems of x and 32
// of y (8 float4 each), all kept in registers. No LDS, no __syncthreads —
// only 3 max-butterflies + 2 sum-butterflies per row. 4 rows per 256-block.

#define ROW_C 2048
#define BLK   256
#define ROWS_PER_BLOCK 4

__device__ __forceinline__ float wave_max(float v) {
#pragma unroll
    for (int off = 32; off; off >>= 1) v = fmaxf(v, __shfl_xor(v, off));
    return v;
}
__device__ __forceinline__ float wave_sum(float v) {
#pragma unroll
    for (int off = 32; off; off >>= 1) v += __shfl_xor(v, off);
    return v;
}

__global__ __launch_bounds__(BLK) void mecl_row_kernel(
        const float* __restrict__ x, const float* __restrict__ y,
        float* __restrict__ ce) {
    const int lane = threadIdx.x & 63;
    const int wave = threadIdx.x >> 6;
    const int row  = blockIdx.x * ROWS_PER_BLOCK + wave;
    const size_t base = (size_t)row * ROW_C;

    const float4* xr = reinterpret_cast<const float4*>(x + base);
    const float4* yr = reinterpret_cast<const float4*>(y + base);

    float4 xv[8], yv[8];
#pragma unroll
    for (int i = 0; i < 8; ++i) xv[i] = xr[lane + 64 * i];
#pragma unroll
    for (int i = 0; i < 8; ++i) yv[i] = yr[lane + 64 * i];

    // Lane-local maxes of x, y, x+y (compiler fuses fmaxf chains to v_max3).
    float mx = -INFINITY, my = -INFINITY, ms = -INFINITY;
#pragma unroll
    for (int i = 0; i < 8; ++i) {
        mx = fmaxf(mx, fmaxf(fmaxf(xv[i].x, xv[i].y), fmaxf(xv[i].z, xv[i].w)));
        my = fmaxf(my, fmaxf(fmaxf(yv[i].x, yv[i].y), fmaxf(yv[i].z, yv[i].w)));
        float s0 = xv[i].x + yv[i].x, s1 = xv[i].y + yv[i].y;
        float s2 = xv[i].z + yv[i].z, s3 = xv[i].w + yv[i].w;
        ms = fmaxf(ms, fmaxf(fmaxf(s0, s1), fmaxf(s2, s3)));
    }

    mx = wave_max(mx);
    my = wave_max(my);
    ms = wave_max(ms);

    float sx = 0.0f, sy = 0.0f;
#pragma unroll
    for (int i = 0; i < 8; ++i) {
        sx += __expf(xv[i].x - mx) + __expf(xv[i].y - mx)
            + __expf(xv[i].z - mx) + __expf(xv[i].w - mx);
        sy += __expf(yv[i].x - my) + __expf(yv[i].y - my)
            + __expf(yv[i].z - my) + __expf(yv[i].w - my);
    }

    sx = wave_sum(sx);
    sy = wave_sum(sy);

    if (lane == 0) {
        float lse_x = mx + __logf(sx);
        float lse_y = my + __logf(sy);
        ce[row] = 0.5f * (lse_x + lse_y - ms);
    }
}

__global__ __launch_bounds__(1024) void mecl_reduce_kernel(
        const float* __restrict__ ws, float* __restrict__ out,
        int n, float inv_n) {
    float s = 0.0f;
    for (int i = threadIdx.x; i < n; i += 1024) s += ws[i];
    s = wave_sum(s);
    __shared__ float sb[16];
    const int wave = threadIdx.x >> 6;
    if ((threadIdx.x & 63) == 0) sb[wave] = s;
    __syncthreads();
    if (threadIdx.x == 0) {
        float tot = 0.0f;
#pragma unroll
        for (int w = 0; w < 16; ++w) tot += sb[w];
        out[0] = tot * inv_n;
    }
}

extern "C" void kernel_launch(void* const* d_in, const int* in_sizes, int n_in,
                              void* d_out, int out_size, void* d_ws, size_t ws_size,
                              hipStream_t stream) {
    const float* x = (const float*)d_in[0];
    const float* y = (const float*)d_in[1];
    float* out = (float*)d_out;

    const int total = in_sizes[0];
    const int N = total / ROW_C;          // 32768 rows
    const float inv_n = 1.0f / (float)N;
    float* ws = (float*)d_ws;             // N floats (ws is 1 GiB, plenty)

    mecl_row_kernel<<<N / ROWS_PER_BLOCK, BLK, 0, stream>>>(x, y, ws);
    mecl_reduce_kernel<<<1, 1024, 0, stream>>>(ws, out, N, inv_n);
}